// Round 1
// baseline (6779.731 us; speedup 1.0000x reference)
//
#include <hip/hip_runtime.h>

// ViTWarpFWarp: forward bilinear-gaussian splat (scatter-add).
// img: (4,128,216,384) f32, flo: (4,2,216,384) f32.
// out = [img_warp (N,C,H,W) | one_warp (N,C,H,W)] f32.
// one_warp is channel-independent -> computed once per pixel into channel-0
// plane, then broadcast.

constexpr int N_ = 4, C_ = 128, H_ = 216, W_ = 384;
constexpr int HW    = H_ * W_;            // 82944
constexpr int TOTAL = N_ * C_ * HW;       // 42467328
constexpr int PIX   = N_ * HW;            // 331776

__global__ __launch_bounds__(256) void ones_scatter_k(const float* __restrict__ flo,
                                                      float* __restrict__ out_ones) {
    int idx = blockIdx.x * 256 + threadIdx.x;
    if (idx >= PIX) return;
    int w  = idx % W_;
    int hn = idx / W_;
    int h  = hn % H_;
    int n  = hn / H_;
    // flo[:,0] = y = W-axis shift; flo[:,1] = x = H-axis shift (per reference _splat)
    float fy = flo[(n * 2 + 0) * HW + h * W_ + w];
    float fx = flo[(n * 2 + 1) * HW + h * W_ + w];
    float fx1 = floorf(fx), fy1 = floorf(fy);
    float dx = fx - fx1, dy = fy - fy1;
    int ix = h + (int)fx1;
    int iy = w + (int)fy1;
    float ex0 = __expf(-dx * dx);
    float ex1 = __expf(-(dx - 1.f) * (dx - 1.f));
    float ey0 = __expf(-dy * dy);
    float ey1 = __expf(-(dy - 1.f) * (dy - 1.f));
    float* plane = out_ones + (size_t)n * C_ * HW;   // channel-0 plane of batch n
    bool bx0 = (unsigned)ix       < (unsigned)H_;
    bool bx1 = (unsigned)(ix + 1) < (unsigned)H_;
    bool by0 = (unsigned)iy       < (unsigned)W_;
    bool by1 = (unsigned)(iy + 1) < (unsigned)W_;
    if (bx0 && by0) atomicAdd(plane + ix * W_ + iy,             ex0 * ey0);
    if (bx0 && by1) atomicAdd(plane + ix * W_ + iy + 1,         ex0 * ey1);
    if (bx1 && by0) atomicAdd(plane + (ix + 1) * W_ + iy,       ex1 * ey0);
    if (bx1 && by1) atomicAdd(plane + (ix + 1) * W_ + iy + 1,   ex1 * ey1);
}

__global__ __launch_bounds__(256) void img_scatter_k(const float* __restrict__ img,
                                                     const float* __restrict__ flo,
                                                     float* __restrict__ out_img) {
    int idx = blockIdx.x * 256 + threadIdx.x;
    if (idx >= TOTAL) return;
    int w   = idx % W_;
    int rem = idx / W_;
    int h   = rem % H_;
    rem /= H_;
    int c = rem % C_;
    int n = rem / C_;
    float fy = flo[(n * 2 + 0) * HW + h * W_ + w];
    float fx = flo[(n * 2 + 1) * HW + h * W_ + w];
    float fx1 = floorf(fx), fy1 = floorf(fy);
    float dx = fx - fx1, dy = fy - fy1;
    int ix = h + (int)fx1;
    int iy = w + (int)fy1;
    float ex0 = __expf(-dx * dx);
    float ex1 = __expf(-(dx - 1.f) * (dx - 1.f));
    float ey0 = __expf(-dy * dy);
    float ey1 = __expf(-(dy - 1.f) * (dy - 1.f));
    float v = img[idx];
    float* plane = out_img + (size_t)(n * C_ + c) * HW;
    bool bx0 = (unsigned)ix       < (unsigned)H_;
    bool bx1 = (unsigned)(ix + 1) < (unsigned)H_;
    bool by0 = (unsigned)iy       < (unsigned)W_;
    bool by1 = (unsigned)(iy + 1) < (unsigned)W_;
    if (bx0 && by0) atomicAdd(plane + ix * W_ + iy,           v * ex0 * ey0);
    if (bx0 && by1) atomicAdd(plane + ix * W_ + iy + 1,       v * ex0 * ey1);
    if (bx1 && by0) atomicAdd(plane + (ix + 1) * W_ + iy,     v * ex1 * ey0);
    if (bx1 && by1) atomicAdd(plane + (ix + 1) * W_ + iy + 1, v * ex1 * ey1);
}

__global__ __launch_bounds__(256) void ones_broadcast_k(float* __restrict__ out_ones) {
    constexpr int HW4 = HW / 4;                 // 20736
    constexpr int TOT = N_ * (C_ - 1) * HW4;
    int idx = blockIdx.x * 256 + threadIdx.x;
    if (idx >= TOT) return;
    int p  = idx % HW4;
    int cn = idx / HW4;
    int c  = 1 + cn % (C_ - 1);
    int n  = cn / (C_ - 1);
    const float4* src = (const float4*)(out_ones + (size_t)n * C_ * HW);
    float4*       dst = (float4*)(out_ones + ((size_t)n * C_ + c) * HW);
    dst[p] = src[p];
}

extern "C" void kernel_launch(void* const* d_in, const int* in_sizes, int n_in,
                              void* d_out, int out_size, void* d_ws, size_t ws_size,
                              hipStream_t stream) {
    const float* img = (const float*)d_in[0];
    const float* flo = (const float*)d_in[1];
    float* out      = (float*)d_out;
    float* out_img  = out;
    float* out_ones = out + (size_t)TOTAL;

    // zero the img_warp accumulator + the 4 channel-0 planes of one_warp
    hipMemsetAsync(out_img, 0, (size_t)TOTAL * sizeof(float), stream);
    for (int n = 0; n < N_; ++n)
        hipMemsetAsync(out_ones + (size_t)n * C_ * HW, 0, HW * sizeof(float), stream);

    ones_scatter_k<<<(PIX + 255) / 256, 256, 0, stream>>>(flo, out_ones);
    img_scatter_k<<<(TOTAL + 255) / 256, 256, 0, stream>>>(img, flo, out_img);
    ones_broadcast_k<<<(N_ * (C_ - 1) * (HW / 4) + 255) / 256, 256, 0, stream>>>(out_ones);
}

// Round 2
// 781.911 us; speedup vs baseline: 8.6707x; 8.6707x over previous
//
#include <hip/hip_runtime.h>

// ViTWarpFWarp: forward bilinear-gaussian splat.
// Strategy R2: invert scatter -> gather.
//   - contributor lists built per output pixel (331k pixels, channel-indep)
//   - img transposed to (N,HW,C) so each contributor read is 512B contiguous
//   - gather: 32 lanes x float4 = 128 channels, zero atomics
//   - one_warp = per-pixel weight sum, broadcast over channels
// Falls back to R1 atomic path if ws_size too small.

constexpr int N_ = 4, C_ = 128, H_ = 216, W_ = 384;
constexpr int HW    = H_ * W_;            // 82944
constexpr int TOTAL = N_ * C_ * HW;       // 42467328
constexpr int PIX   = N_ * HW;            // 331776
constexpr int SCAN_BLOCKS = PIX / 256;    // 1296

// ---------------- workspace layout (float/uint elements) ----------------
// [0, TOTAL)                  imgT   (N,HW,C)
// [TOTAL, 2T)                 outT   (N,HW,C)
// [2T, 2T+PIX)                counts (uint)
// [.. +PIX)                   cursor (uint)
// [.. +PIX)                   offsets(uint)
// [.. +4096)                  blocksums (uint)
// [.. +PIX)                   ones_plane (float)
// [.. +4*PIX)                 entry_s (uint)
// [.. +4*PIX)                 entry_w (float)
constexpr size_t OFF_IMGT   = 0;
constexpr size_t OFF_OUTT   = (size_t)TOTAL;
constexpr size_t OFF_COUNTS = 2ull * TOTAL;
constexpr size_t OFF_CURSOR = OFF_COUNTS + PIX;
constexpr size_t OFF_OFFS   = OFF_CURSOR + PIX;
constexpr size_t OFF_BS     = OFF_OFFS + PIX;
constexpr size_t OFF_ONES   = OFF_BS + 4096;
constexpr size_t OFF_ES     = OFF_ONES + PIX;
constexpr size_t OFF_EW     = OFF_ES + 4ull * PIX;
constexpr size_t WS_ELEMS   = OFF_EW + 4ull * PIX;
constexpr size_t WS_BYTES   = WS_ELEMS * 4;

// ---------------- helpers ----------------
__device__ inline void corner_math(float fx, float fy, int& ifx, int& ify,
                                   float& ex0, float& ex1, float& ey0, float& ey1) {
    float fx1 = floorf(fx), fy1 = floorf(fy);
    float dx = fx - fx1, dy = fy - fy1;
    ifx = (int)fx1; ify = (int)fy1;
    ex0 = __expf(-dx * dx);
    ex1 = __expf(-(dx - 1.f) * (dx - 1.f));
    ey0 = __expf(-dy * dy);
    ey1 = __expf(-(dy - 1.f) * (dy - 1.f));
}

// ---------------- pass 0: transpose img (C,HW) -> (HW,C) per batch ----------
__global__ __launch_bounds__(256) void transpose_fwd_k(const float* __restrict__ img,
                                                       float* __restrict__ imgT) {
    __shared__ float tile[32][33];
    int n   = blockIdx.z;
    int hw0 = blockIdx.x * 32;
    int c0  = blockIdx.y * 32;
    const float* src = img  + (size_t)n * C_ * HW;
    float*       dst = imgT + (size_t)n * HW * C_;
    int tx = threadIdx.x, ty = threadIdx.y;
#pragma unroll
    for (int r = 0; r < 32; r += 8)
        tile[ty + r][tx] = src[(size_t)(c0 + ty + r) * HW + hw0 + tx];
    __syncthreads();
#pragma unroll
    for (int r = 0; r < 32; r += 8)
        dst[(size_t)(hw0 + ty + r) * C_ + c0 + tx] = tile[tx][ty + r];
}

// ---------------- pass 1: count contributors per target ----------------
__global__ __launch_bounds__(256) void count_k(const float* __restrict__ flo,
                                               unsigned int* __restrict__ counts) {
    int idx = blockIdx.x * 256 + threadIdx.x;   // over PIX
    if (idx >= PIX) return;
    int s = idx % HW, n = idx / HW;
    int h = s / W_, w = s % W_;
    float fy = flo[(n * 2 + 0) * HW + s];
    float fx = flo[(n * 2 + 1) * HW + s];
    int ifx, ify; float ex0, ex1, ey0, ey1;
    corner_math(fx, fy, ifx, ify, ex0, ex1, ey0, ey1);
    int ix = h + ifx, iy = w + ify;
    unsigned int* base = counts + (size_t)n * HW;
    bool bx0 = (unsigned)ix       < (unsigned)H_;
    bool bx1 = (unsigned)(ix + 1) < (unsigned)H_;
    bool by0 = (unsigned)iy       < (unsigned)W_;
    bool by1 = (unsigned)(iy + 1) < (unsigned)W_;
    if (bx0 && by0) atomicAdd(base + ix * W_ + iy, 1u);
    if (bx0 && by1) atomicAdd(base + ix * W_ + iy + 1, 1u);
    if (bx1 && by0) atomicAdd(base + (ix + 1) * W_ + iy, 1u);
    if (bx1 && by1) atomicAdd(base + (ix + 1) * W_ + iy + 1, 1u);
}

// ---------------- pass 2: exclusive scan (3 kernels) ----------------
__global__ __launch_bounds__(256) void scan_local_k(const unsigned int* __restrict__ counts,
                                                    unsigned int* __restrict__ offs,
                                                    unsigned int* __restrict__ bs) {
    __shared__ unsigned int tmp[256];
    int tid = threadIdx.x;
    int i = blockIdx.x * 256 + tid;
    unsigned int v = counts[i];
    tmp[tid] = v;
    __syncthreads();
    for (int off = 1; off < 256; off <<= 1) {
        unsigned int t = (tid >= off) ? tmp[tid - off] : 0u;
        __syncthreads();
        tmp[tid] += t;
        __syncthreads();
    }
    offs[i] = tmp[tid] - v;                 // exclusive within block
    if (tid == 255) bs[blockIdx.x] = tmp[tid];
}

__global__ __launch_bounds__(256) void scan_bs_k(unsigned int* __restrict__ bs) {
    __shared__ unsigned int tmp[256];
    constexpr int IT = 6;                    // 256*6 = 1536 >= 1296
    int tid = threadIdx.x;
    unsigned int v[IT]; unsigned int sum = 0;
#pragma unroll
    for (int i = 0; i < IT; ++i) {
        int j = tid * IT + i;
        v[i] = (j < SCAN_BLOCKS) ? bs[j] : 0u;
        sum += v[i];
    }
    tmp[tid] = sum;
    __syncthreads();
    for (int off = 1; off < 256; off <<= 1) {
        unsigned int t = (tid >= off) ? tmp[tid - off] : 0u;
        __syncthreads();
        tmp[tid] += t;
        __syncthreads();
    }
    unsigned int run = tmp[tid] - sum;       // exclusive
#pragma unroll
    for (int i = 0; i < IT; ++i) {
        int j = tid * IT + i;
        if (j < SCAN_BLOCKS) { unsigned int old = v[i]; bs[j] = run; run += old; }
    }
}

__global__ __launch_bounds__(256) void scan_add_k(unsigned int* __restrict__ offs,
                                                  const unsigned int* __restrict__ bs) {
    int i = blockIdx.x * 256 + threadIdx.x;
    offs[i] += bs[blockIdx.x];
}

// ---------------- pass 3: fill entries ----------------
__global__ __launch_bounds__(256) void fill_k(const float* __restrict__ flo,
                                              const unsigned int* __restrict__ offs,
                                              unsigned int* __restrict__ cursor,
                                              unsigned int* __restrict__ entry_s,
                                              float* __restrict__ entry_w) {
    int idx = blockIdx.x * 256 + threadIdx.x;
    if (idx >= PIX) return;
    int s = idx % HW, n = idx / HW;
    int h = s / W_, w = s % W_;
    float fy = flo[(n * 2 + 0) * HW + s];
    float fx = flo[(n * 2 + 1) * HW + s];
    int ifx, ify; float ex0, ex1, ey0, ey1;
    corner_math(fx, fy, ifx, ify, ex0, ex1, ey0, ey1);
    int ix = h + ifx, iy = w + ify;
    bool bx[2] = { (unsigned)ix < (unsigned)H_, (unsigned)(ix + 1) < (unsigned)H_ };
    bool by[2] = { (unsigned)iy < (unsigned)W_, (unsigned)(iy + 1) < (unsigned)W_ };
    float exw[2] = { ex0, ex1 }, eyw[2] = { ey0, ey1 };
#pragma unroll
    for (int a = 0; a < 2; ++a) {
#pragma unroll
        for (int b = 0; b < 2; ++b) {
            if (bx[a] && by[b]) {
                int t = n * HW + (ix + a) * W_ + (iy + b);
                unsigned int slot = atomicAdd(cursor + t, 1u);
                unsigned int e = offs[t] + slot;
                entry_s[e] = (unsigned int)s;
                entry_w[e] = exw[a] * eyw[b];
            }
        }
    }
}

// ---------------- pass 4: gather ----------------
__global__ __launch_bounds__(256) void gather_k(const float* __restrict__ imgT,
                                                const unsigned int* __restrict__ counts,
                                                const unsigned int* __restrict__ offs,
                                                const unsigned int* __restrict__ entry_s,
                                                const float* __restrict__ entry_w,
                                                float* __restrict__ outT,
                                                float* __restrict__ ones_plane) {
    int pl = threadIdx.x >> 5;               // 0..7 pixel within block
    int cg = threadIdx.x & 31;               // channel group (4 ch each)
    int t  = blockIdx.x * 8 + pl;            // global target pixel, < PIX
    int n = t / HW, p = t % HW;
    unsigned int k   = counts[t];
    unsigned int off = offs[t];
    float4 acc = make_float4(0.f, 0.f, 0.f, 0.f);
    float wsum = 0.f;
    const float4* srcBase = (const float4*)(imgT + (size_t)n * HW * C_);
    for (unsigned int j = 0; j < k; ++j) {
        unsigned int s = entry_s[off + j];
        float wgt     = entry_w[off + j];
        float4 v = srcBase[(size_t)s * (C_ / 4) + cg];
        acc.x += wgt * v.x; acc.y += wgt * v.y;
        acc.z += wgt * v.z; acc.w += wgt * v.w;
        wsum += wgt;
    }
    ((float4*)(outT + ((size_t)n * HW + p) * C_))[cg] = acc;
    if (cg == 0) ones_plane[t] = wsum;
}

// ---------------- pass 5: transpose back (HW,C) -> (C,HW) ----------------
__global__ __launch_bounds__(256) void transpose_back_k(const float* __restrict__ outT,
                                                        float* __restrict__ out) {
    __shared__ float tile[32][33];
    int n   = blockIdx.z;
    int hw0 = blockIdx.x * 32;
    int c0  = blockIdx.y * 32;
    const float* src = outT + (size_t)n * HW * C_;
    float*       dst = out  + (size_t)n * C_ * HW;
    int tx = threadIdx.x, ty = threadIdx.y;
#pragma unroll
    for (int r = 0; r < 32; r += 8)
        tile[ty + r][tx] = src[(size_t)(hw0 + ty + r) * C_ + c0 + tx];
    __syncthreads();
#pragma unroll
    for (int r = 0; r < 32; r += 8)
        dst[(size_t)(c0 + ty + r) * HW + hw0 + tx] = tile[tx][ty + r];
}

// ---------------- pass 6: broadcast ones plane over channels -------------
__global__ __launch_bounds__(256) void ones_bcast_k(const float* __restrict__ ones_plane,
                                                    float* __restrict__ out_ones) {
    constexpr int HW4 = HW / 4;
    int idx = blockIdx.x * 256 + threadIdx.x;    // over N*C*HW4
    int p  = idx % HW4;
    int cn = idx / HW4;
    int c  = cn % C_;
    int n  = cn / C_;
    const float4* src = (const float4*)(ones_plane + (size_t)n * HW);
    float4*       dst = (float4*)(out_ones + ((size_t)n * C_ + c) * HW);
    dst[p] = src[p];
}

// ================= R1 fallback (atomic scatter) =================
__global__ __launch_bounds__(256) void fb_ones_scatter_k(const float* __restrict__ flo,
                                                         float* __restrict__ out_ones) {
    int idx = blockIdx.x * 256 + threadIdx.x;
    if (idx >= PIX) return;
    int w = idx % W_; int hn = idx / W_; int h = hn % H_; int n = hn / H_;
    float fy = flo[(n * 2 + 0) * HW + h * W_ + w];
    float fx = flo[(n * 2 + 1) * HW + h * W_ + w];
    int ifx, ify; float ex0, ex1, ey0, ey1;
    corner_math(fx, fy, ifx, ify, ex0, ex1, ey0, ey1);
    int ix = h + ifx, iy = w + ify;
    float* plane = out_ones + (size_t)n * C_ * HW;
    if ((unsigned)ix < (unsigned)H_ && (unsigned)iy < (unsigned)W_) atomicAdd(plane + ix * W_ + iy, ex0 * ey0);
    if ((unsigned)ix < (unsigned)H_ && (unsigned)(iy+1) < (unsigned)W_) atomicAdd(plane + ix * W_ + iy + 1, ex0 * ey1);
    if ((unsigned)(ix+1) < (unsigned)H_ && (unsigned)iy < (unsigned)W_) atomicAdd(plane + (ix+1) * W_ + iy, ex1 * ey0);
    if ((unsigned)(ix+1) < (unsigned)H_ && (unsigned)(iy+1) < (unsigned)W_) atomicAdd(plane + (ix+1) * W_ + iy + 1, ex1 * ey1);
}

__global__ __launch_bounds__(256) void fb_img_scatter_k(const float* __restrict__ img,
                                                        const float* __restrict__ flo,
                                                        float* __restrict__ out_img) {
    int idx = blockIdx.x * 256 + threadIdx.x;
    if (idx >= TOTAL) return;
    int w = idx % W_; int rem = idx / W_; int h = rem % H_; rem /= H_;
    int c = rem % C_; int n = rem / C_;
    float fy = flo[(n * 2 + 0) * HW + h * W_ + w];
    float fx = flo[(n * 2 + 1) * HW + h * W_ + w];
    int ifx, ify; float ex0, ex1, ey0, ey1;
    corner_math(fx, fy, ifx, ify, ex0, ex1, ey0, ey1);
    int ix = h + ifx, iy = w + ify;
    float v = img[idx];
    float* plane = out_img + (size_t)(n * C_ + c) * HW;
    if ((unsigned)ix < (unsigned)H_ && (unsigned)iy < (unsigned)W_) atomicAdd(plane + ix * W_ + iy, v * ex0 * ey0);
    if ((unsigned)ix < (unsigned)H_ && (unsigned)(iy+1) < (unsigned)W_) atomicAdd(plane + ix * W_ + iy + 1, v * ex0 * ey1);
    if ((unsigned)(ix+1) < (unsigned)H_ && (unsigned)iy < (unsigned)W_) atomicAdd(plane + (ix+1) * W_ + iy, v * ex1 * ey0);
    if ((unsigned)(ix+1) < (unsigned)H_ && (unsigned)(iy+1) < (unsigned)W_) atomicAdd(plane + (ix+1) * W_ + iy + 1, v * ex1 * ey1);
}

__global__ __launch_bounds__(256) void fb_ones_bcast_k(float* __restrict__ out_ones) {
    constexpr int HW4 = HW / 4;
    constexpr int TOT = N_ * (C_ - 1) * HW4;
    int idx = blockIdx.x * 256 + threadIdx.x;
    if (idx >= TOT) return;
    int p = idx % HW4; int cn = idx / HW4;
    int c = 1 + cn % (C_ - 1); int n = cn / (C_ - 1);
    const float4* src = (const float4*)(out_ones + (size_t)n * C_ * HW);
    float4*       dst = (float4*)(out_ones + ((size_t)n * C_ + c) * HW);
    dst[p] = src[p];
}

// ================= launch =================
extern "C" void kernel_launch(void* const* d_in, const int* in_sizes, int n_in,
                              void* d_out, int out_size, void* d_ws, size_t ws_size,
                              hipStream_t stream) {
    const float* img = (const float*)d_in[0];
    const float* flo = (const float*)d_in[1];
    float* out      = (float*)d_out;
    float* out_img  = out;
    float* out_ones = out + (size_t)TOTAL;

    if (ws_size < WS_BYTES) {
        // fallback: R1 atomic path
        hipMemsetAsync(out_img, 0, (size_t)TOTAL * sizeof(float), stream);
        for (int n = 0; n < N_; ++n)
            hipMemsetAsync(out_ones + (size_t)n * C_ * HW, 0, HW * sizeof(float), stream);
        fb_ones_scatter_k<<<(PIX + 255) / 256, 256, 0, stream>>>(flo, out_ones);
        fb_img_scatter_k<<<(TOTAL + 255) / 256, 256, 0, stream>>>(img, flo, out_img);
        fb_ones_bcast_k<<<(N_ * (C_ - 1) * (HW / 4) + 255) / 256, 256, 0, stream>>>(out_ones);
        return;
    }

    float* ws = (float*)d_ws;
    float*        imgT    = ws + OFF_IMGT;
    float*        outT    = ws + OFF_OUTT;
    unsigned int* counts  = (unsigned int*)(ws + OFF_COUNTS);
    unsigned int* cursor  = (unsigned int*)(ws + OFF_CURSOR);
    unsigned int* offs    = (unsigned int*)(ws + OFF_OFFS);
    unsigned int* bs      = (unsigned int*)(ws + OFF_BS);
    float*        ones_pl = ws + OFF_ONES;
    unsigned int* entry_s = (unsigned int*)(ws + OFF_ES);
    float*        entry_w = ws + OFF_EW;

    // zero counts+cursor (contiguous)
    hipMemsetAsync(counts, 0, 2ull * PIX * sizeof(unsigned int), stream);

    dim3 tb(32, 8);
    transpose_fwd_k<<<dim3(HW / 32, C_ / 32, N_), tb, 0, stream>>>(img, imgT);
    count_k<<<SCAN_BLOCKS, 256, 0, stream>>>(flo, counts);
    scan_local_k<<<SCAN_BLOCKS, 256, 0, stream>>>(counts, offs, bs);
    scan_bs_k<<<1, 256, 0, stream>>>(bs);
    scan_add_k<<<SCAN_BLOCKS, 256, 0, stream>>>(offs, bs);
    fill_k<<<SCAN_BLOCKS, 256, 0, stream>>>(flo, offs, cursor, entry_s, entry_w);
    gather_k<<<PIX / 8, 256, 0, stream>>>(imgT, counts, offs, entry_s, entry_w, outT, ones_pl);
    transpose_back_k<<<dim3(HW / 32, C_ / 32, N_), tb, 0, stream>>>(outT, out_img);
    ones_bcast_k<<<(N_ * C_ * (HW / 4) + 255) / 256, 256, 0, stream>>>(ones_pl, out_ones);
}